// Round 4
// baseline (254.540 us; speedup 1.0000x reference)
//
#include <hip/hip_runtime.h>
#include <math.h>

#define Bv 4096
#define Sv 64
#define Ev 128
#define Hv 256
#define Cv 18
#define NKB 12       // rnn K blocks (384/32)
#define FKB 8        // fc K blocks (256/32)
#define Mrows 16

using bfrag = __attribute__((ext_vector_type(8))) short;
using f4v   = __attribute__((ext_vector_type(4))) float;

#define FP8_WSCALE 1048576.0f          // 2^20 on w_lo
#define FP8_ASCALE 8.0f                // 2^3 on a
#define FP8_DESCALE (1.0f / 8388608.0f) // 2^-23

__device__ inline void split_bf16(float v, unsigned& hb, unsigned& lb) {
    unsigned u = __float_as_uint(v);
    hb = (u + 0x7FFFu + ((u >> 16) & 1u)) >> 16;          // RNE bf16(v)
    float hf = __uint_as_float(hb << 16);
    float l = v - hf;
    unsigned ul = __float_as_uint(l);
    lb = (ul + 0x7FFFu + ((ul >> 16) & 1u)) >> 16;        // RNE bf16(v - hi)
}

__device__ inline float fast_tanh(float x) {
    float e = __expf(x + x);
    return 1.0f - 2.0f * __builtin_amdgcn_rcpf(e + 1.0f);
}

// pack 4 floats (scaled) into 4 e4m3 bytes
__device__ inline unsigned pk_fp8x4(float a, float b, float c, float d, float s) {
    int r = __builtin_amdgcn_cvt_pk_fp8_f32(a * s, b * s, 0, false);
    r = __builtin_amdgcn_cvt_pk_fp8_f32(c * s, d * s, r, true);
    return (unsigned)r;
}

// ---- kernel A: build MFMA fragments: rnn W (hi bf16 + lo fp8), fc W1 ----
__global__ void build_frags(const float* __restrict__ W_ih,
                            const float* __restrict__ W_hh,
                            const float* __restrict__ W1,
                            unsigned* __restrict__ wfh,  unsigned* __restrict__ wfl8,
                            unsigned* __restrict__ wf1h, unsigned* __restrict__ wf1l8) {
    int f = blockIdx.x * 256 + threadIdx.x;   // 0..20479
    bool isrnn = f < 12288;
    int g = isrnn ? f : f - 12288;
    int lane = g & 63, tile = (g >> 6) & 15, kb = g >> 10;
    int q = lane >> 4, col = lane & 15;
    int n = tile * 16 + col;
    float v[8]; unsigned hs[8];
    float ls[8];
    #pragma unroll
    for (int j = 0; j < 8; ++j) {
        int k = kb * 32 + q * 8 + j;
        float x;
        if (isrnn) x = (k < Ev) ? W_ih[n * Ev + k] : W_hh[n * Hv + (k - Ev)];
        else       x = W1[n * Hv + k];
        v[j] = x;
        unsigned hb, lb;
        split_bf16(x, hb, lb);
        hs[j] = hb;
        ls[j] = x - __uint_as_float(hb << 16);
    }
    unsigned* oh = (isrnn ? wfh : wf1h) + (size_t)g * 4;
    unsigned* ol = (isrnn ? wfl8 : wf1l8) + (size_t)g * 2;
    #pragma unroll
    for (int d = 0; d < 4; ++d) oh[d] = hs[2 * d] | (hs[2 * d + 1] << 16);
    ol[0] = pk_fp8x4(ls[0], ls[1], ls[2], ls[3], FP8_WSCALE);
    ol[1] = pk_fp8x4(ls[4], ls[5], ls[6], ls[7], FP8_WSCALE);
}

// ---- kernel B: block-local recurrence, W resident (144 regs) ----
// LDS buffer (words): per half: AH [12*256] | AL [12*256] | A8 [12*128] = 7680
__global__ __launch_bounds__(512, 2) void rnn_kernel(
    const int* __restrict__ x_in, const int* __restrict__ x_len,
    const float* __restrict__ emb,
    const unsigned* __restrict__ wfh, const unsigned* __restrict__ wfl8,
    const float* __restrict__ b_ih, const float* __restrict__ b_hh,
    float* __restrict__ last)
{
    __shared__ unsigned SH[2 * 7680];   // 61440 B

    const int tid = threadIdx.x;
    const int lane = tid & 63, w = tid >> 6;     // wave 0..7
    const int q = lane >> 4, col = lane & 15;
    const int rb = blockIdx.x * Mrows;

    // resident W: tiles 2w, 2w+1 -> hi bf16 (96 regs) + lo fp8 (48 regs)
    bfrag wh[2][NKB];
    long  wl8[2][NKB];
    #pragma unroll
    for (int i = 0; i < 2; ++i)
        #pragma unroll
        for (int kb = 0; kb < NKB; ++kb) {
            int fid = (kb * 16 + (2 * w + i)) * 64 + lane;
            wh[i][kb]  = *reinterpret_cast<const bfrag*>(&wfh[(size_t)fid * 4]);
            wl8[i][kb] = *reinterpret_cast<const long*>(&wfl8[(size_t)fid * 2]);
        }

    float bc[2][4];
    #pragma unroll
    for (int i = 0; i < 2; ++i)
        #pragma unroll
        for (int r = 0; r < 4; ++r) {
            int n = (2 * w + i) * 16 + 4 * q + r;
            bc[i][r] = b_ih[n] + b_hh[n];
        }
    const int len_c = x_len[rb + col];

    // zero h region of buffer 0 (AH/AL kb4..11, A8 kb4..11)
    for (int u = tid; u < 2048; u += 512) { SH[1024 + u] = 0u; SH[3072 + 1024 + u] = 0u; }
    for (int u = tid; u < 1024; u += 512) SH[6144 + 512 + u] = 0u;

    // emb staging geometry: thread stages 4 consecutive k of one row
    const int em  = tid >> 5;            // row 0..15
    const int ek  = (tid & 31) * 4;      // k 0..124
    const int ekb = ek >> 5;
    const int edl = ((ek >> 3) & 3) * 16 + em;
    const int ewo = (ek & 4) >> 1;       // uint2 word offset
    const int esel = (ek >> 2) & 1;      // a8 dword select

    // stage emb for t=0 into buffer 0
    {
        int idx = x_in[(rb + em) * Sv];
        float4 ev = *(const float4*)&emb[(size_t)idx * Ev + ek];
        unsigned h0, h1, h2, h3, l0, l1, l2, l3;
        split_bf16(ev.x, h0, l0); split_bf16(ev.y, h1, l1);
        split_bf16(ev.z, h2, l2); split_bf16(ev.w, h3, l3);
        int a = ekb * 256 + edl * 4 + ewo;
        *reinterpret_cast<uint2*>(&SH[a])        = make_uint2(h0 | (h1 << 16), h2 | (h3 << 16));
        *reinterpret_cast<uint2*>(&SH[a + 3072]) = make_uint2(l0 | (l1 << 16), l2 | (l3 << 16));
        SH[6144 + ekb * 128 + edl * 2 + esel] = pk_fp8x4(ev.x, ev.y, ev.z, ev.w, FP8_ASCALE);
    }
    __syncthreads();

    #pragma unroll 1
    for (int t = 0; t < Sv; ++t) {
        const int rbuf = (t & 1) * 7680;
        const int wbuf = ((t + 1) & 1) * 7680;

        float4 ev;
        const bool pre = (t < Sv - 1);
        if (pre) {
            int idx = x_in[(rb + em) * Sv + t + 1];
            ev = *(const float4*)&emb[(size_t)idx * Ev + ek];
        }

        f4v accB0 = {0.f, 0.f, 0.f, 0.f}, accB1 = accB0, acc80 = accB0, acc81 = accB0;

        #pragma unroll
        for (int kb = 0; kb < NKB; ++kb) {
            const int ab = rbuf + kb * 256 + lane * 4;
            bfrag ah = *reinterpret_cast<const bfrag*>(&SH[ab]);
            bfrag al = *reinterpret_cast<const bfrag*>(&SH[ab + 3072]);
            long  a8 = *reinterpret_cast<const long*>(&SH[rbuf + 6144 + kb * 128 + lane * 2]);
            accB0 = __builtin_amdgcn_mfma_f32_16x16x32_bf16(wh[0][kb], ah, accB0, 0, 0, 0);
            accB1 = __builtin_amdgcn_mfma_f32_16x16x32_bf16(wh[1][kb], ah, accB1, 0, 0, 0);
            acc80 = __builtin_amdgcn_mfma_f32_16x16x32_fp8_fp8(wl8[0][kb], a8, acc80, 0, 0, 0);
            acc81 = __builtin_amdgcn_mfma_f32_16x16x32_fp8_fp8(wl8[1][kb], a8, acc81, 0, 0, 0);
            accB0 = __builtin_amdgcn_mfma_f32_16x16x32_bf16(wh[0][kb], al, accB0, 0, 0, 0);
            accB1 = __builtin_amdgcn_mfma_f32_16x16x32_bf16(wh[1][kb], al, accB1, 0, 0, 0);
        }

        // epilogue: lane holds h[m=col][n = ti*16 + 4q + r]
        #pragma unroll
        for (int i = 0; i < 2; ++i) {
            f4v acc = (i == 0) ? accB0 : accB1;
            f4v a8c = (i == 0) ? acc80 : acc81;
            const int ti = 2 * w + i;
            float hv[4]; unsigned hb[4], lb[4];
            #pragma unroll
            for (int r = 0; r < 4; ++r) {
                hv[r] = fast_tanh(acc[r] + a8c[r] * FP8_DESCALE + bc[i][r]);
                split_bf16(hv[r], hb[r], lb[r]);
            }
            const int dl = ((ti & 1) * 2 + (q >> 1)) * 16 + col;
            const int wo = (q & 1) * 2;
            int a = wbuf + (4 + (ti >> 1)) * 256 + dl * 4 + wo;
            *reinterpret_cast<uint2*>(&SH[a])        = make_uint2(hb[0] | (hb[1] << 16), hb[2] | (hb[3] << 16));
            *reinterpret_cast<uint2*>(&SH[a + 3072]) = make_uint2(lb[0] | (lb[1] << 16), lb[2] | (lb[3] << 16));
            SH[wbuf + 6144 + (4 + (ti >> 1)) * 128 + dl * 2 + (q & 1)] =
                pk_fp8x4(hv[0], hv[1], hv[2], hv[3], FP8_ASCALE);
            if (t == len_c - 1) {
                *reinterpret_cast<float4*>(&last[(size_t)(rb + col) * Hv + ti * 16 + 4 * q]) =
                    make_float4(hv[0], hv[1], hv[2], hv[3]);
            }
        }
        if (pre) {
            unsigned h0, h1, h2, h3, l0, l1, l2, l3;
            split_bf16(ev.x, h0, l0); split_bf16(ev.y, h1, l1);
            split_bf16(ev.z, h2, l2); split_bf16(ev.w, h3, l3);
            int a = wbuf + ekb * 256 + edl * 4 + ewo;
            *reinterpret_cast<uint2*>(&SH[a])        = make_uint2(h0 | (h1 << 16), h2 | (h3 << 16));
            *reinterpret_cast<uint2*>(&SH[a + 3072]) = make_uint2(l0 | (l1 << 16), l2 | (l3 << 16));
            SH[wbuf + 6144 + ekb * 128 + edl * 2 + esel] = pk_fp8x4(ev.x, ev.y, ev.z, ev.w, FP8_ASCALE);
        }
        __syncthreads();
    }
}

// ---- kernel C: MFMA FC1(relu) + VALU FC2 ----
// LDS words: AH2 [8*256]=2048 | AL2 2048 | A82 [8*128]=1024 | y 16*260 f32
__global__ __launch_bounds__(256, 1) void fc_kernel(
    const float* __restrict__ last,
    const unsigned* __restrict__ wf1h, const unsigned* __restrict__ wf1l8,
    const float* __restrict__ b1, const float* __restrict__ W2,
    const float* __restrict__ b2, float* __restrict__ out)
{
    __shared__ unsigned SH[5120 + 4160];
    float* yb = reinterpret_cast<float*>(&SH[5120]);

    const int tid = threadIdx.x;
    const int lane = tid & 63, wv = tid >> 6;    // wave 0..3
    const int q = lane >> 4, col = lane & 15;
    const int rb = blockIdx.x * Mrows;

    // stage last -> fragment LDS (hi/lo bf16 + fp8)
    {
        const int em = tid >> 4;
        const int k0 = (tid & 15) * 16;
        #pragma unroll
        for (int q4 = 0; q4 < 4; ++q4) {
            int k = k0 + 4 * q4;
            float4 v = *(const float4*)&last[(size_t)(rb + em) * Hv + k];
            int kb = k >> 5, kin = k & 31;
            int dl = (kin >> 3) * 16 + em;
            int wo = (kin & 4) >> 1, sel = (kin >> 2) & 1;
            unsigned h0, h1, h2, h3, l0, l1, l2, l3;
            split_bf16(v.x, h0, l0); split_bf16(v.y, h1, l1);
            split_bf16(v.z, h2, l2); split_bf16(v.w, h3, l3);
            int a = kb * 256 + dl * 4 + wo;
            *reinterpret_cast<uint2*>(&SH[a])        = make_uint2(h0 | (h1 << 16), h2 | (h3 << 16));
            *reinterpret_cast<uint2*>(&SH[a + 2048]) = make_uint2(l0 | (l1 << 16), l2 | (l3 << 16));
            SH[4096 + kb * 128 + dl * 2 + sel] = pk_fp8x4(v.x, v.y, v.z, v.w, FP8_ASCALE);
        }
    }
    __syncthreads();

    f4v accB[4], acc8[4];
    #pragma unroll
    for (int i = 0; i < 4; ++i) { f4v z = {0.f, 0.f, 0.f, 0.f}; accB[i] = z; acc8[i] = z; }

    #pragma unroll
    for (int kb = 0; kb < FKB; ++kb) {
        const int ab = kb * 256 + lane * 4;
        bfrag ah = *reinterpret_cast<const bfrag*>(&SH[ab]);
        bfrag al = *reinterpret_cast<const bfrag*>(&SH[ab + 2048]);
        long  a8 = *reinterpret_cast<const long*>(&SH[4096 + kb * 128 + lane * 2]);
        #pragma unroll
        for (int i = 0; i < 4; ++i) {
            int fid = (kb * 16 + (4 * wv + i)) * 64 + lane;
            bfrag w1h = *reinterpret_cast<const bfrag*>(&wf1h[(size_t)fid * 4]);
            long  w1l = *reinterpret_cast<const long*>(&wf1l8[(size_t)fid * 2]);
            accB[i] = __builtin_amdgcn_mfma_f32_16x16x32_bf16(w1h, ah, accB[i], 0, 0, 0);
            acc8[i] = __builtin_amdgcn_mfma_f32_16x16x32_fp8_fp8(w1l, a8, acc8[i], 0, 0, 0);
            accB[i] = __builtin_amdgcn_mfma_f32_16x16x32_bf16(w1h, al, accB[i], 0, 0, 0);
        }
    }

    // y[m=col][n] = relu(acc + b1[n])
    #pragma unroll
    for (int i = 0; i < 4; ++i) {
        int n0 = (4 * wv + i) * 16 + 4 * q;
        float4 b1v = *(const float4*)&b1[n0];
        float4 yv;
        yv.x = fmaxf(accB[i][0] + acc8[i][0] * FP8_DESCALE + b1v.x, 0.f);
        yv.y = fmaxf(accB[i][1] + acc8[i][1] * FP8_DESCALE + b1v.y, 0.f);
        yv.z = fmaxf(accB[i][2] + acc8[i][2] * FP8_DESCALE + b1v.z, 0.f);
        yv.w = fmaxf(accB[i][3] + acc8[i][3] * FP8_DESCALE + b1v.w, 0.f);
        *reinterpret_cast<float4*>(&yb[col * 260 + n0]) = yv;
    }
    __syncthreads();

    // FC2: 16 x 18 dots of length 256
    for (int p = tid; p < Mrows * Cv; p += 256) {
        int r = p & 15, cc = p >> 4;
        float s = b2[cc];
        for (int k4 = 0; k4 < Hv / 4; ++k4) {
            float4 yv = *reinterpret_cast<const float4*>(&yb[r * 260 + 4 * k4]);
            float4 wv2 = *(const float4*)&W2[cc * Hv + 4 * k4];
            s = fmaf(yv.x, wv2.x, s);
            s = fmaf(yv.y, wv2.y, s);
            s = fmaf(yv.z, wv2.z, s);
            s = fmaf(yv.w, wv2.w, s);
        }
        out[(rb + r) * Cv + cc] = s;
    }
}

extern "C" void kernel_launch(void* const* d_in, const int* in_sizes, int n_in,
                              void* d_out, int out_size, void* d_ws, size_t ws_size,
                              hipStream_t stream) {
    const int*   x_in  = (const int*)  d_in[0];
    const int*   x_len = (const int*)  d_in[1];
    const float* emb   = (const float*)d_in[2];
    const float* W_ih  = (const float*)d_in[3];
    const float* W_hh  = (const float*)d_in[4];
    const float* b_ih  = (const float*)d_in[5];
    const float* b_hh  = (const float*)d_in[6];
    const float* W1    = (const float*)d_in[7];
    const float* b1    = (const float*)d_in[8];
    const float* W2    = (const float*)d_in[9];
    const float* b2    = (const float*)d_in[10];
    float* out = (float*)d_out;

    float*    last  = (float*)d_ws;                       // 4 MB
    unsigned* wfh   = (unsigned*)(last + (size_t)Bv * Hv);// 12288*16 B
    unsigned* wfl8  = wfh + 12288 * 4;                    // 12288*8 B
    unsigned* wf1h  = wfl8 + 12288 * 2;                   // 8192*16 B
    unsigned* wf1l8 = wf1h + 8192 * 4;                    // 8192*8 B

    build_frags<<<80, 256, 0, stream>>>(W_ih, W_hh, W1, wfh, wfl8, wf1h, wf1l8);
    rnn_kernel<<<Bv / Mrows, 512, 0, stream>>>(x_in, x_len, emb, wfh, wfl8, b_ih, b_hh, last);
    fc_kernel<<<Bv / Mrows, 256, 0, stream>>>(last, wf1h, wf1l8, b1, W2, b2, out);
}

// Round 5
// 208.762 us; speedup vs baseline: 1.2193x; 1.2193x over previous
//
#include <hip/hip_runtime.h>
#include <hip/hip_fp16.h>
#include <math.h>

#define Bv 4096
#define Sv 64
#define Ev 128
#define Hv 256
#define Cv 18
#define NKB 12       // rnn K blocks (384/32)
#define FKB 8        // fc K blocks (256/32)
#define Mrows 16
#define WRDS 4608    // LDS words per rnn buffer: AH 12*256 + A8 6*256

typedef _Float16 hfrag __attribute__((ext_vector_type(8)));
using f4v = __attribute__((ext_vector_type(4))) float;

#define FP8_WSCALE 1048576.0f            // 2^20 on w_lo
#define FP8_ASCALE 8.0f                  // 2^3 on a
#define FP8_DESCALE (1.0f / 8388608.0f)  // 2^-23

__device__ inline float fast_tanh(float x) {
    float e = __expf(x + x);
    return 1.0f - 2.0f * __builtin_amdgcn_rcpf(e + 1.0f);
}

__device__ inline unsigned pk_h2(float a, float b) {
    unsigned ua = __half_as_ushort(__float2half_rn(a));
    unsigned ub = __half_as_ushort(__float2half_rn(b));
    return ua | (ub << 16);
}

// pack 4 floats (scaled) into 4 e4m3 bytes
__device__ inline unsigned pk_fp8x4(float a, float b, float c, float d, float s) {
    int r = __builtin_amdgcn_cvt_pk_fp8_f32(a * s, b * s, 0, false);
    r = __builtin_amdgcn_cvt_pk_fp8_f32(c * s, d * s, r, true);
    return (unsigned)r;
}

__device__ inline long mklong(unsigned lo, unsigned hi) {
    return (long)(((unsigned long)hi << 32) | (unsigned long)lo);
}

// ---- kernel A: build MFMA fragments (fp16 hi + fp8 lo) for rnn W and fc W1 ----
__global__ void build_frags(const float* __restrict__ W_ih,
                            const float* __restrict__ W_hh,
                            const float* __restrict__ W1,
                            unsigned* __restrict__ wfh,  unsigned* __restrict__ wfl8,
                            unsigned* __restrict__ wf1h, unsigned* __restrict__ wf1l8) {
    int f = blockIdx.x * 256 + threadIdx.x;   // 0..20479
    bool isrnn = f < 12288;
    int g = isrnn ? f : f - 12288;
    int lane = g & 63, tile = (g >> 6) & 15, kb = g >> 10;
    int q = lane >> 4, col = lane & 15;
    int n = tile * 16 + col;
    unsigned hu[8]; float lf[8];
    #pragma unroll
    for (int j = 0; j < 8; ++j) {
        int k = kb * 32 + q * 8 + j;
        float x;
        if (isrnn) x = (k < Ev) ? W_ih[n * Ev + k] : W_hh[n * Hv + (k - Ev)];
        else       x = W1[n * Hv + k];
        __half h = __float2half_rn(x);
        hu[j] = __half_as_ushort(h);
        lf[j] = x - __half2float(h);
    }
    unsigned* oh = (isrnn ? wfh : wf1h) + (size_t)g * 4;
    unsigned* ol = (isrnn ? wfl8 : wf1l8) + (size_t)g * 2;
    #pragma unroll
    for (int d = 0; d < 4; ++d) oh[d] = hu[2 * d] | (hu[2 * d + 1] << 16);
    ol[0] = pk_fp8x4(lf[0], lf[1], lf[2], lf[3], FP8_WSCALE);
    ol[1] = pk_fp8x4(lf[4], lf[5], lf[6], lf[7], FP8_WSCALE);
}

// ---- kernel B: block-local recurrence, W pinned resident (144 regs) ----
// LDS per buffer (words): AH [12*256] fp16-frags | A8 [6*256] fp8 kb-pairs
__global__ __launch_bounds__(512, 2) void rnn_kernel(
    const int* __restrict__ x_in, const int* __restrict__ x_len,
    const float* __restrict__ emb,
    const unsigned* __restrict__ wfh, const unsigned* __restrict__ wfl8,
    const float* __restrict__ b_ih, const float* __restrict__ b_hh,
    float* __restrict__ last)
{
    __shared__ unsigned SH[2 * WRDS];   // 36864 B

    const int tid = threadIdx.x;
    const int lane = tid & 63, w = tid >> 6;     // wave 0..7
    const int q = lane >> 4, col = lane & 15;
    const int rb = blockIdx.x * Mrows;

    // resident W: tiles 2w, 2w+1 -> fp16 hi (96 regs) + fp8 lo (48 regs)
    hfrag wh[2][NKB];
    long  wl8[2][NKB];
    #pragma unroll
    for (int i = 0; i < 2; ++i)
        #pragma unroll
        for (int kb = 0; kb < NKB; ++kb) {
            int fid = (kb * 16 + (2 * w + i)) * 64 + lane;
            wh[i][kb]  = *reinterpret_cast<const hfrag*>(&wfh[(size_t)fid * 4]);
            wl8[i][kb] = *reinterpret_cast<const long*>(&wfl8[(size_t)fid * 2]);
        }
    // pin: make W non-rematerializable so the allocator keeps it in VGPRs
    #pragma unroll
    for (int i = 0; i < 2; ++i)
        #pragma unroll
        for (int kb = 0; kb < NKB; ++kb) {
            asm volatile("" : "+v"(wh[i][kb]));
            asm volatile("" : "+v"(wl8[i][kb]));
        }

    float bc[2][4];
    #pragma unroll
    for (int i = 0; i < 2; ++i)
        #pragma unroll
        for (int r = 0; r < 4; ++r) {
            int n = (2 * w + i) * 16 + 4 * q + r;
            bc[i][r] = b_ih[n] + b_hh[n];
        }
    const int len_c = x_len[rb + col];

    // zero h region of buffer 0: AH kb4..11, A8 kbp2..5
    for (int u = tid; u < 2048; u += 512) SH[1024 + u] = 0u;
    for (int u = tid; u < 1024; u += 512) SH[3072 + 512 + u] = 0u;

    // emb staging geometry: thread stages 4 consecutive k of one row
    const int em   = tid >> 5;            // row 0..15
    const int ek   = (tid & 31) * 4;      // k 0..124
    const int ekb  = ek >> 5;             // kb 0..3
    const int edl  = ((ek >> 3) & 3) * 16 + em;
    const int esel = (ek >> 2) & 1;
    const int eah  = ekb * 256 + edl * 4 + esel * 2;
    const int ea8  = 3072 + (ekb >> 1) * 256 + edl * 4 + ((ekb & 1) * 2 + esel);

    // stage emb for t=0 into buffer 0
    {
        int idx = x_in[(rb + em) * Sv];
        float4 ev = *(const float4*)&emb[(size_t)idx * Ev + ek];
        *reinterpret_cast<uint2*>(&SH[eah]) =
            make_uint2(pk_h2(ev.x, ev.y), pk_h2(ev.z, ev.w));
        SH[ea8] = pk_fp8x4(ev.x, ev.y, ev.z, ev.w, FP8_ASCALE);
    }
    __syncthreads();

    #pragma unroll 1
    for (int t = 0; t < Sv; ++t) {
        const int rbuf = (t & 1) * WRDS;
        const int wbuf = ((t + 1) & 1) * WRDS;

        float4 ev;
        const bool pre = (t < Sv - 1);
        if (pre) {
            int idx = x_in[(rb + em) * Sv + t + 1];
            ev = *(const float4*)&emb[(size_t)idx * Ev + ek];
        }

        f4v accH0 = {0.f, 0.f, 0.f, 0.f}, accH1 = accH0, acc80 = accH0, acc81 = accH0;

        uint4 a8p;
        #pragma unroll
        for (int kb = 0; kb < NKB; ++kb) {
            hfrag ah = *reinterpret_cast<const hfrag*>(&SH[rbuf + kb * 256 + lane * 4]);
            if ((kb & 1) == 0)
                a8p = *reinterpret_cast<const uint4*>(&SH[rbuf + 3072 + (kb >> 1) * 256 + lane * 4]);
            long a8 = (kb & 1) ? mklong(a8p.z, a8p.w) : mklong(a8p.x, a8p.y);
            accH0 = __builtin_amdgcn_mfma_f32_16x16x32_f16(wh[0][kb], ah, accH0, 0, 0, 0);
            accH1 = __builtin_amdgcn_mfma_f32_16x16x32_f16(wh[1][kb], ah, accH1, 0, 0, 0);
            acc80 = __builtin_amdgcn_mfma_f32_16x16x32_fp8_fp8(wl8[0][kb], a8, acc80, 0, 0, 0);
            acc81 = __builtin_amdgcn_mfma_f32_16x16x32_fp8_fp8(wl8[1][kb], a8, acc81, 0, 0, 0);
        }

        // epilogue: lane holds h[m=col][n = ti*16 + 4q + r]
        #pragma unroll
        for (int i = 0; i < 2; ++i) {
            f4v acc = (i == 0) ? accH0 : accH1;
            f4v c8  = (i == 0) ? acc80 : acc81;
            const int ti = 2 * w + i;
            float hv[4];
            #pragma unroll
            for (int r = 0; r < 4; ++r)
                hv[r] = fast_tanh(acc[r] + c8[r] * FP8_DESCALE + bc[i][r]);
            const int dl = ((ti & 1) * 2 + (q >> 1)) * 16 + col;
            const int aAH = wbuf + (4 + (ti >> 1)) * 256 + dl * 4 + (q & 1) * 2;
            *reinterpret_cast<uint2*>(&SH[aAH]) =
                make_uint2(pk_h2(hv[0], hv[1]), pk_h2(hv[2], hv[3]));
            const int aA8 = wbuf + 3072 + (2 + (ti >> 2)) * 256 + dl * 4 +
                            (((ti >> 1) & 1) * 2 + (q & 1));
            SH[aA8] = pk_fp8x4(hv[0], hv[1], hv[2], hv[3], FP8_ASCALE);
            if (t == len_c - 1) {
                *reinterpret_cast<float4*>(&last[(size_t)(rb + col) * Hv + ti * 16 + 4 * q]) =
                    make_float4(hv[0], hv[1], hv[2], hv[3]);
            }
        }
        if (pre) {
            *reinterpret_cast<uint2*>(&SH[wbuf + eah]) =
                make_uint2(pk_h2(ev.x, ev.y), pk_h2(ev.z, ev.w));
            SH[wbuf + ea8] = pk_fp8x4(ev.x, ev.y, ev.z, ev.w, FP8_ASCALE);
        }
        __syncthreads();
    }
}

// ---- kernel C: MFMA FC1(relu) + VALU FC2, 2-term fp16+fp8 ----
// LDS words: AH2 [8*256]=2048 | A82 [4*256]=1024 | yb 16*260 f32
__global__ __launch_bounds__(256, 1) void fc_kernel(
    const float* __restrict__ last,
    const unsigned* __restrict__ wf1h, const unsigned* __restrict__ wf1l8,
    const float* __restrict__ b1, const float* __restrict__ W2,
    const float* __restrict__ b2, float* __restrict__ out)
{
    __shared__ unsigned SH[3072 + 4160];
    float* yb = reinterpret_cast<float*>(&SH[3072]);

    const int tid = threadIdx.x;
    const int lane = tid & 63, wv = tid >> 6;    // wave 0..3
    const int q = lane >> 4, col = lane & 15;
    const int rb = blockIdx.x * Mrows;

    // stage last -> fp16 + fp8 fragment LDS
    {
        const int em = tid >> 4;
        const int k0 = (tid & 15) * 16;
        #pragma unroll
        for (int q4 = 0; q4 < 4; ++q4) {
            int k = k0 + 4 * q4;
            float4 v = *(const float4*)&last[(size_t)(rb + em) * Hv + k];
            int kb = k >> 5, koff = k & 31;
            int dl = (koff >> 3) * 16 + em;
            int sel = (k >> 2) & 1;
            int aAH = kb * 256 + dl * 4 + sel * 2;
            *reinterpret_cast<uint2*>(&SH[aAH]) =
                make_uint2(pk_h2(v.x, v.y), pk_h2(v.z, v.w));
            SH[2048 + (kb >> 1) * 256 + dl * 4 + ((kb & 1) * 2 + sel)] =
                pk_fp8x4(v.x, v.y, v.z, v.w, FP8_ASCALE);
        }
    }
    __syncthreads();

    f4v accH[4], acc8[4];
    #pragma unroll
    for (int i = 0; i < 4; ++i) { f4v z = {0.f, 0.f, 0.f, 0.f}; accH[i] = z; acc8[i] = z; }

    uint4 a8p;
    #pragma unroll
    for (int kb = 0; kb < FKB; ++kb) {
        hfrag ah = *reinterpret_cast<const hfrag*>(&SH[kb * 256 + lane * 4]);
        if ((kb & 1) == 0)
            a8p = *reinterpret_cast<const uint4*>(&SH[2048 + (kb >> 1) * 256 + lane * 4]);
        long a8 = (kb & 1) ? mklong(a8p.z, a8p.w) : mklong(a8p.x, a8p.y);
        #pragma unroll
        for (int i = 0; i < 4; ++i) {
            int fid = (kb * 16 + (4 * wv + i)) * 64 + lane;
            hfrag w1h = *reinterpret_cast<const hfrag*>(&wf1h[(size_t)fid * 4]);
            long  w1l = *reinterpret_cast<const long*>(&wf1l8[(size_t)fid * 2]);
            accH[i] = __builtin_amdgcn_mfma_f32_16x16x32_f16(w1h, ah, accH[i], 0, 0, 0);
            acc8[i] = __builtin_amdgcn_mfma_f32_16x16x32_fp8_fp8(w1l, a8, acc8[i], 0, 0, 0);
        }
    }

    // y[m=col][n] = relu(acc + b1[n])
    #pragma unroll
    for (int i = 0; i < 4; ++i) {
        int n0 = (4 * wv + i) * 16 + 4 * q;
        float4 b1v = *(const float4*)&b1[n0];
        float4 yv;
        yv.x = fmaxf(accH[i][0] + acc8[i][0] * FP8_DESCALE + b1v.x, 0.f);
        yv.y = fmaxf(accH[i][1] + acc8[i][1] * FP8_DESCALE + b1v.y, 0.f);
        yv.z = fmaxf(accH[i][2] + acc8[i][2] * FP8_DESCALE + b1v.z, 0.f);
        yv.w = fmaxf(accH[i][3] + acc8[i][3] * FP8_DESCALE + b1v.w, 0.f);
        *reinterpret_cast<float4*>(&yb[col * 260 + n0]) = yv;
    }
    __syncthreads();

    // FC2: 16 x 18 dots of length 256
    for (int p = tid; p < Mrows * Cv; p += 256) {
        int r = p & 15, cc = p >> 4;
        float s = b2[cc];
        for (int k4 = 0; k4 < Hv / 4; ++k4) {
            float4 yv = *reinterpret_cast<const float4*>(&yb[r * 260 + 4 * k4]);
            float4 wv2 = *(const float4*)&W2[cc * Hv + 4 * k4];
            s = fmaf(yv.x, wv2.x, s);
            s = fmaf(yv.y, wv2.y, s);
            s = fmaf(yv.z, wv2.z, s);
            s = fmaf(yv.w, wv2.w, s);
        }
        out[(rb + r) * Cv + cc] = s;
    }
}

extern "C" void kernel_launch(void* const* d_in, const int* in_sizes, int n_in,
                              void* d_out, int out_size, void* d_ws, size_t ws_size,
                              hipStream_t stream) {
    const int*   x_in  = (const int*)  d_in[0];
    const int*   x_len = (const int*)  d_in[1];
    const float* emb   = (const float*)d_in[2];
    const float* W_ih  = (const float*)d_in[3];
    const float* W_hh  = (const float*)d_in[4];
    const float* b_ih  = (const float*)d_in[5];
    const float* b_hh  = (const float*)d_in[6];
    const float* W1    = (const float*)d_in[7];
    const float* b1    = (const float*)d_in[8];
    const float* W2    = (const float*)d_in[9];
    const float* b2    = (const float*)d_in[10];
    float* out = (float*)d_out;

    float*    last  = (float*)d_ws;                        // 4 MB
    unsigned* wfh   = (unsigned*)(last + (size_t)Bv * Hv); // 12288*16 B
    unsigned* wfl8  = wfh + 12288 * 4;                     // 12288*8 B
    unsigned* wf1h  = wfl8 + 12288 * 2;                    // 8192*16 B
    unsigned* wf1l8 = wf1h + 8192 * 4;                     // 8192*8 B

    build_frags<<<80, 256, 0, stream>>>(W_ih, W_hh, W1, wfh, wfl8, wf1h, wf1l8);
    rnn_kernel<<<Bv / Mrows, 512, 0, stream>>>(x_in, x_len, emb, wfh, wfl8, b_ih, b_hh, last);
    fc_kernel<<<Bv / Mrows, 256, 0, stream>>>(last, wf1h, wf1l8, b1, W2, b2, out);
}

// Round 6
// 188.780 us; speedup vs baseline: 1.3483x; 1.1058x over previous
//
#include <hip/hip_runtime.h>
#include <hip/hip_fp16.h>
#include <math.h>

#define Bv 4096
#define Sv 64
#define Ev 128
#define Hv 256
#define Cv 18
#define Mrows 16
#define WRDS 4096    // words per step buffer: AH 12*256 | A8 4*256

typedef _Float16 hfrag __attribute__((ext_vector_type(8)));
using f4v = __attribute__((ext_vector_type(4))) float;

#define FP8_WSCALE 1048576.0f            // 2^20 on w_lo
#define FP8_ASCALE 8.0f                  // 2^3 on a
#define FP8_DESCALE (1.0f / 8388608.0f)  // 2^-23

__device__ inline float fast_tanh(float x) {
    float e = __expf(x + x);
    return 1.0f - 2.0f * __builtin_amdgcn_rcpf(e + 1.0f);
}

__device__ inline unsigned pk_h2(float a, float b) {
    unsigned ua = __half_as_ushort(__float2half_rn(a));
    unsigned ub = __half_as_ushort(__float2half_rn(b));
    return ua | (ub << 16);
}

__device__ inline unsigned pk_fp8x4(float a, float b, float c, float d, float s) {
    int r = __builtin_amdgcn_cvt_pk_fp8_f32(a * s, b * s, 0, false);
    r = __builtin_amdgcn_cvt_pk_fp8_f32(c * s, d * s, r, true);
    return (unsigned)r;
}

__device__ inline long mklong(unsigned lo, unsigned hi) {
    return (long)(((unsigned long)hi << 32) | (unsigned long)lo);
}

// ---- kernel A: build MFMA fragments (fp16 hi + fp8 lo) for rnn W and fc W1 ----
__global__ void build_frags(const float* __restrict__ W_ih,
                            const float* __restrict__ W_hh,
                            const float* __restrict__ W1,
                            unsigned* __restrict__ wfh,  unsigned* __restrict__ wfl8,
                            unsigned* __restrict__ wf1h, unsigned* __restrict__ wf1l8) {
    int f = blockIdx.x * 256 + threadIdx.x;   // 0..20479
    bool isrnn = f < 12288;
    int g = isrnn ? f : f - 12288;
    int lane = g & 63, tile = (g >> 6) & 15, kb = g >> 10;
    int q = lane >> 4, col = lane & 15;
    int n = tile * 16 + col;
    unsigned hu[8]; float lf[8];
    #pragma unroll
    for (int j = 0; j < 8; ++j) {
        int k = kb * 32 + q * 8 + j;
        float x;
        if (isrnn) x = (k < Ev) ? W_ih[n * Ev + k] : W_hh[n * Hv + (k - Ev)];
        else       x = W1[n * Hv + k];
        __half h = __float2half_rn(x);
        hu[j] = __half_as_ushort(h);
        lf[j] = x - __half2float(h);
    }
    unsigned* oh = (isrnn ? wfh : wf1h) + (size_t)g * 4;
    unsigned* ol = (isrnn ? wfl8 : wf1l8) + (size_t)g * 2;
    #pragma unroll
    for (int d = 0; d < 4; ++d) oh[d] = hu[2 * d] | (hu[2 * d + 1] << 16);
    ol[0] = pk_fp8x4(lf[0], lf[1], lf[2], lf[3], FP8_WSCALE);
    ol[1] = pk_fp8x4(lf[4], lf[5], lf[6], lf[7], FP8_WSCALE);
}

// ---- kernel B: fused recurrence + FC head, W pinned resident ----
__global__ __launch_bounds__(512, 2) void rnn_fused(
    const int* __restrict__ x_in, const int* __restrict__ x_len,
    const float* __restrict__ emb,
    const unsigned* __restrict__ wfh, const unsigned* __restrict__ wfl8,
    const unsigned* __restrict__ wf1h, const unsigned* __restrict__ wf1l8,
    const float* __restrict__ b_ih, const float* __restrict__ b_hh,
    const float* __restrict__ b1, const float* __restrict__ W2,
    const float* __restrict__ b2, float* __restrict__ out)
{
    __shared__ unsigned SH[2 * WRDS];   // 32 KB step buffers
    __shared__ unsigned LF[3072];       // 12 KB last-h fragments (AH 8*256 | A8 4*256)
    float* yb = reinterpret_cast<float*>(SH);   // fc y buffer aliases SH after loop

    const int tid = threadIdx.x;
    const int lane = tid & 63, w = tid >> 6;     // wave 0..7
    const int q = lane >> 4, col = lane & 15;
    const int rb = blockIdx.x * Mrows;

    // resident W: tiles 2w, 2w+1 -> fp16 hi all 12 kb (96 regs) + fp8 lo kb4..11 (32 regs)
    hfrag wh[2][12];
    long  wl8[2][8];
    #pragma unroll
    for (int i = 0; i < 2; ++i) {
        #pragma unroll
        for (int kb = 0; kb < 12; ++kb) {
            int fid = (kb * 16 + (2 * w + i)) * 64 + lane;
            wh[i][kb] = *reinterpret_cast<const hfrag*>(&wfh[(size_t)fid * 4]);
        }
        #pragma unroll
        for (int kp = 0; kp < 8; ++kp) {
            int fid = ((kp + 4) * 16 + (2 * w + i)) * 64 + lane;
            wl8[i][kp] = *reinterpret_cast<const long*>(&wfl8[(size_t)fid * 2]);
        }
    }
    #pragma unroll
    for (int i = 0; i < 2; ++i) {
        #pragma unroll
        for (int kb = 0; kb < 12; ++kb) asm volatile("" : "+v"(wh[i][kb]));
        #pragma unroll
        for (int kp = 0; kp < 8; ++kp) asm volatile("" : "+v"(wl8[i][kp]));
    }

    // bias vectors (fold into MFMA C-init)
    f4v bcv[2];
    #pragma unroll
    for (int i = 0; i < 2; ++i)
        #pragma unroll
        for (int r = 0; r < 4; ++r) {
            int n = (2 * w + i) * 16 + 4 * q + r;
            bcv[i][r] = b_ih[n] + b_hh[n];
        }
    const int len_c = x_len[rb + col];
    int tmax = len_c;
    #pragma unroll
    for (int m = 1; m < 16; m <<= 1) {
        int o = __shfl_xor(tmax, m, 64);
        tmax = tmax > o ? tmax : o;
    }

    // zero h-region of buffer 0: AH kb4..11 + A8 all
    for (int u = tid; u < 2048; u += 512) SH[1024 + u] = 0u;
    for (int u = tid; u < 1024; u += 512) SH[3072 + u] = 0u;

    // emb staging geometry: thread stages 4 consecutive k of one row (f16 only)
    const int em  = tid >> 5;            // row 0..15
    const int ek  = (tid & 31) * 4;      // k 0..124
    const int eoff = (ek >> 5) * 256 + (((ek >> 3) & 3) * 16 + em) * 4 + ((ek >> 2) & 1) * 2;
    const int* xrow = x_in + (rb + em) * Sv;

    {
        float4 ev = *(const float4*)&emb[(size_t)xrow[0] * Ev + ek];
        *reinterpret_cast<uint2*>(&SH[eoff]) =
            make_uint2(pk_h2(ev.x, ev.y), pk_h2(ev.z, ev.w));
    }
    __syncthreads();

    #pragma unroll 1
    for (int t = 0; t < tmax; ++t) {
        const int rbuf = (t & 1) * WRDS;
        const int wbuf = ((t + 1) & 1) * WRDS;
        const bool pre = (t + 1 < tmax);
        float4 ev;
        if (pre) ev = *(const float4*)&emb[(size_t)xrow[t + 1] * Ev + ek];

        // 8 accumulator chains, bias folded into the even f16 chains
        f4v aHe0 = bcv[0], aHe1 = bcv[1];
        f4v z = {0.f, 0.f, 0.f, 0.f};
        f4v aHo0 = z, aHo1 = z, a8e0 = z, a8e1 = z, a8o0 = z, a8o1 = z;

        #pragma unroll
        for (int kb = 0; kb < 4; ++kb) {
            hfrag ah = *reinterpret_cast<const hfrag*>(&SH[rbuf + kb * 256 + lane * 4]);
            if (kb & 1) {
                aHo0 = __builtin_amdgcn_mfma_f32_16x16x32_f16(wh[0][kb], ah, aHo0, 0, 0, 0);
                aHo1 = __builtin_amdgcn_mfma_f32_16x16x32_f16(wh[1][kb], ah, aHo1, 0, 0, 0);
            } else {
                aHe0 = __builtin_amdgcn_mfma_f32_16x16x32_f16(wh[0][kb], ah, aHe0, 0, 0, 0);
                aHe1 = __builtin_amdgcn_mfma_f32_16x16x32_f16(wh[1][kb], ah, aHe1, 0, 0, 0);
            }
        }
        #pragma unroll
        for (int p = 0; p < 4; ++p) {
            const int kbE = 4 + 2 * p;
            hfrag ahE = *reinterpret_cast<const hfrag*>(&SH[rbuf + kbE * 256 + lane * 4]);
            hfrag ahO = *reinterpret_cast<const hfrag*>(&SH[rbuf + (kbE + 1) * 256 + lane * 4]);
            uint4 a8p = *reinterpret_cast<const uint4*>(&SH[rbuf + 3072 + p * 256 + lane * 4]);
            long a8E = mklong(a8p.x, a8p.y), a8O = mklong(a8p.z, a8p.w);
            aHe0 = __builtin_amdgcn_mfma_f32_16x16x32_f16(wh[0][kbE], ahE, aHe0, 0, 0, 0);
            aHe1 = __builtin_amdgcn_mfma_f32_16x16x32_f16(wh[1][kbE], ahE, aHe1, 0, 0, 0);
            a8e0 = __builtin_amdgcn_mfma_f32_16x16x32_fp8_fp8(wl8[0][2 * p], a8E, a8e0, 0, 0, 0);
            a8e1 = __builtin_amdgcn_mfma_f32_16x16x32_fp8_fp8(wl8[1][2 * p], a8E, a8e1, 0, 0, 0);
            aHo0 = __builtin_amdgcn_mfma_f32_16x16x32_f16(wh[0][kbE + 1], ahO, aHo0, 0, 0, 0);
            aHo1 = __builtin_amdgcn_mfma_f32_16x16x32_f16(wh[1][kbE + 1], ahO, aHo1, 0, 0, 0);
            a8o0 = __builtin_amdgcn_mfma_f32_16x16x32_fp8_fp8(wl8[0][2 * p + 1], a8O, a8o0, 0, 0, 0);
            a8o1 = __builtin_amdgcn_mfma_f32_16x16x32_fp8_fp8(wl8[1][2 * p + 1], a8O, a8o1, 0, 0, 0);
        }

        // epilogue: lane holds h[m=col][n = ti*16 + 4q + r]
        #pragma unroll
        for (int i = 0; i < 2; ++i) {
            f4v s  = (i == 0) ? (aHe0 + aHo0) : (aHe1 + aHo1);
            f4v s8 = (i == 0) ? (a8e0 + a8o0) : (a8e1 + a8o1);
            const int ti = 2 * w + i;
            float hv[4];
            #pragma unroll
            for (int r = 0; r < 4; ++r)
                hv[r] = fast_tanh(s[r] + s8[r] * FP8_DESCALE);
            const int dl = ((ti & 1) * 2 + (q >> 1)) * 16 + col;
            const uint2 hu = make_uint2(pk_h2(hv[0], hv[1]), pk_h2(hv[2], hv[3]));
            const unsigned a8w = pk_fp8x4(hv[0], hv[1], hv[2], hv[3], FP8_ASCALE);
            const int offAH = (ti >> 1) * 256 + dl * 4 + (q & 1) * 2;
            const int offA8 = (ti >> 2) * 256 + dl * 4 + ((ti >> 1) & 1) * 2 + (q & 1);
            *reinterpret_cast<uint2*>(&SH[wbuf + 1024 + offAH]) = hu;
            SH[wbuf + 3072 + offA8] = a8w;
            if (t == len_c - 1) {
                *reinterpret_cast<uint2*>(&LF[offAH]) = hu;
                LF[2048 + offA8] = a8w;
            }
        }
        if (pre)
            *reinterpret_cast<uint2*>(&SH[wbuf + eoff]) =
                make_uint2(pk_h2(ev.x, ev.y), pk_h2(ev.z, ev.w));
        __syncthreads();
    }

    // ---- fused FC1 (MFMA, fp16+fp8) ----
    f4v f0, f1, f80, f81;
    {
        float4 bb0 = *(const float4*)&b1[(2 * w) * 16 + 4 * q];
        float4 bb1 = *(const float4*)&b1[(2 * w + 1) * 16 + 4 * q];
        f0 = (f4v){bb0.x, bb0.y, bb0.z, bb0.w};
        f1 = (f4v){bb1.x, bb1.y, bb1.z, bb1.w};
        f4v z = {0.f, 0.f, 0.f, 0.f};
        f80 = z; f81 = z;
    }
    uint4 a8p;
    #pragma unroll
    for (int kb = 0; kb < 8; ++kb) {
        hfrag ah = *reinterpret_cast<const hfrag*>(&LF[kb * 256 + lane * 4]);
        if ((kb & 1) == 0)
            a8p = *reinterpret_cast<const uint4*>(&LF[2048 + (kb >> 1) * 256 + lane * 4]);
        long a8 = (kb & 1) ? mklong(a8p.z, a8p.w) : mklong(a8p.x, a8p.y);
        int fid0 = (kb * 16 + 2 * w) * 64 + lane;
        int fid1 = fid0 + 64;
        hfrag w0 = *reinterpret_cast<const hfrag*>(&wf1h[(size_t)fid0 * 4]);
        hfrag w1 = *reinterpret_cast<const hfrag*>(&wf1h[(size_t)fid1 * 4]);
        long  l0 = *reinterpret_cast<const long*>(&wf1l8[(size_t)fid0 * 2]);
        long  l1 = *reinterpret_cast<const long*>(&wf1l8[(size_t)fid1 * 2]);
        f0  = __builtin_amdgcn_mfma_f32_16x16x32_f16(w0, ah, f0, 0, 0, 0);
        f1  = __builtin_amdgcn_mfma_f32_16x16x32_f16(w1, ah, f1, 0, 0, 0);
        f80 = __builtin_amdgcn_mfma_f32_16x16x32_fp8_fp8(l0, a8, f80, 0, 0, 0);
        f81 = __builtin_amdgcn_mfma_f32_16x16x32_fp8_fp8(l1, a8, f81, 0, 0, 0);
    }

    // y = relu(...) into yb (aliases SH; no wave reads SH at this point)
    #pragma unroll
    for (int i = 0; i < 2; ++i) {
        int n0 = (2 * w + i) * 16 + 4 * q;
        f4v s = (i == 0) ? f0 : f1;
        f4v s8 = (i == 0) ? f80 : f81;
        float4 yv;
        yv.x = fmaxf(s[0] + s8[0] * FP8_DESCALE, 0.f);
        yv.y = fmaxf(s[1] + s8[1] * FP8_DESCALE, 0.f);
        yv.z = fmaxf(s[2] + s8[2] * FP8_DESCALE, 0.f);
        yv.w = fmaxf(s[3] + s8[3] * FP8_DESCALE, 0.f);
        *reinterpret_cast<float4*>(&yb[col * 260 + n0]) = yv;
    }
    __syncthreads();

    // ---- FC2: 16 x 18 dots of length 256 ----
    if (tid < Mrows * Cv) {
        int r = tid & 15, cc = tid >> 4;
        float s = b2[cc];
        #pragma unroll 8
        for (int k4 = 0; k4 < Hv / 4; ++k4) {
            float4 yv = *reinterpret_cast<const float4*>(&yb[r * 260 + 4 * k4]);
            float4 wv2 = *(const float4*)&W2[cc * Hv + 4 * k4];
            s = fmaf(yv.x, wv2.x, s);
            s = fmaf(yv.y, wv2.y, s);
            s = fmaf(yv.z, wv2.z, s);
            s = fmaf(yv.w, wv2.w, s);
        }
        out[(rb + r) * Cv + cc] = s;
    }
}

extern "C" void kernel_launch(void* const* d_in, const int* in_sizes, int n_in,
                              void* d_out, int out_size, void* d_ws, size_t ws_size,
                              hipStream_t stream) {
    const int*   x_in  = (const int*)  d_in[0];
    const int*   x_len = (const int*)  d_in[1];
    const float* emb   = (const float*)d_in[2];
    const float* W_ih  = (const float*)d_in[3];
    const float* W_hh  = (const float*)d_in[4];
    const float* b_ih  = (const float*)d_in[5];
    const float* b_hh  = (const float*)d_in[6];
    const float* W1    = (const float*)d_in[7];
    const float* b1    = (const float*)d_in[8];
    const float* W2    = (const float*)d_in[9];
    const float* b2    = (const float*)d_in[10];
    float* out = (float*)d_out;

    unsigned* wfh   = (unsigned*)d_ws;        // 12288*16 B
    unsigned* wfl8  = wfh + 12288 * 4;        // 12288*8 B
    unsigned* wf1h  = wfl8 + 12288 * 2;       // 8192*16 B
    unsigned* wf1l8 = wf1h + 8192 * 4;        // 8192*8 B

    build_frags<<<80, 256, 0, stream>>>(W_ih, W_hh, W1, wfh, wfl8, wf1h, wf1l8);
    rnn_fused<<<Bv / Mrows, 512, 0, stream>>>(x_in, x_len, emb, wfh, wfl8,
                                              wf1h, wf1l8, b_ih, b_hh,
                                              b1, W2, b2, out);
}

// Round 7
// 170.122 us; speedup vs baseline: 1.4962x; 1.1097x over previous
//
#include <hip/hip_runtime.h>
#include <hip/hip_fp16.h>
#include <math.h>

#define Bv 4096
#define Sv 64
#define Ev 128
#define Hv 256
#define Cv 18
#define Mrows 16
#define WRDS 4096    // words per step buffer: AH kb0..11 (emb 0-3, h 4-11) | A8 p0..3 at 3072

typedef _Float16 hfrag __attribute__((ext_vector_type(8)));
using f4v = __attribute__((ext_vector_type(4))) float;

#define FP8_WSCALE 1048576.0f            // 2^20 on w_lo
#define FP8_ASCALE 8.0f                  // 2^3 on a
#define FP8_DESCALE (1.0f / 8388608.0f)  // 2^-23

// XOR swizzle: permutes bits 2-4 by a function of higher bits. Preserves
// bits 0-1 (b128/uint4/uint2 contiguity) and injective per region. Makes the
// scattered epilogue/staging writes bank-balanced while keeping reads the
// canonical conflict-free lane*16B pattern.
__device__ inline int SW(int o) {
    return o ^ ((((o >> 5) ^ (o >> 8)) & 7) << 2);
}

__device__ inline float fast_tanh(float x) {
    float e = __expf(x + x);
    return 1.0f - 2.0f * __builtin_amdgcn_rcpf(e + 1.0f);
}

__device__ inline unsigned pk_h2(float a, float b) {
    unsigned ua = __half_as_ushort(__float2half_rn(a));
    unsigned ub = __half_as_ushort(__float2half_rn(b));
    return ua | (ub << 16);
}

__device__ inline unsigned pk_fp8x4(float a, float b, float c, float d, float s) {
    int r = __builtin_amdgcn_cvt_pk_fp8_f32(a * s, b * s, 0, false);
    r = __builtin_amdgcn_cvt_pk_fp8_f32(c * s, d * s, r, true);
    return (unsigned)r;
}

__device__ inline long mklong(unsigned lo, unsigned hi) {
    return (long)(((unsigned long)hi << 32) | (unsigned long)lo);
}

// ---- kernel A: build MFMA fragments (fp16 hi + fp8 lo) for rnn W and fc W1 ----
__global__ void build_frags(const float* __restrict__ W_ih,
                            const float* __restrict__ W_hh,
                            const float* __restrict__ W1,
                            unsigned* __restrict__ wfh,  unsigned* __restrict__ wfl8,
                            unsigned* __restrict__ wf1h, unsigned* __restrict__ wf1l8) {
    int f = blockIdx.x * 256 + threadIdx.x;   // 0..20479
    bool isrnn = f < 12288;
    int g = isrnn ? f : f - 12288;
    int lane = g & 63, tile = (g >> 6) & 15, kb = g >> 10;
    int q = lane >> 4, col = lane & 15;
    int n = tile * 16 + col;
    unsigned hu[8]; float lf[8];
    #pragma unroll
    for (int j = 0; j < 8; ++j) {
        int k = kb * 32 + q * 8 + j;
        float x;
        if (isrnn) x = (k < Ev) ? W_ih[n * Ev + k] : W_hh[n * Hv + (k - Ev)];
        else       x = W1[n * Hv + k];
        __half h = __float2half_rn(x);
        hu[j] = __half_as_ushort(h);
        lf[j] = x - __half2float(h);
    }
    unsigned* oh = (isrnn ? wfh : wf1h) + (size_t)g * 4;
    unsigned* ol = (isrnn ? wfl8 : wf1l8) + (size_t)g * 2;
    #pragma unroll
    for (int d = 0; d < 4; ++d) oh[d] = hu[2 * d] | (hu[2 * d + 1] << 16);
    ol[0] = pk_fp8x4(lf[0], lf[1], lf[2], lf[3], FP8_WSCALE);
    ol[1] = pk_fp8x4(lf[4], lf[5], lf[6], lf[7], FP8_WSCALE);
}

// ---- kernel B: fused recurrence + FC head, W pinned resident ----
__global__ __launch_bounds__(512, 2) void rnn_fused(
    const int* __restrict__ x_in, const int* __restrict__ x_len,
    const float* __restrict__ emb,
    const unsigned* __restrict__ wfh, const unsigned* __restrict__ wfl8,
    const unsigned* __restrict__ wf1h, const unsigned* __restrict__ wf1l8,
    const float* __restrict__ b_ih, const float* __restrict__ b_hh,
    const float* __restrict__ b1, const float* __restrict__ W2,
    const float* __restrict__ b2, float* __restrict__ out)
{
    __shared__ unsigned SH[2 * WRDS];   // 32 KB step buffers
    __shared__ unsigned LF[3072];       // 12 KB last-h fragments (AH 8*256 | A8 4*256)
    __shared__ int sidx[Mrows * Sv];    // 4 KB token ids, [t*16 + m]
    float* yb = reinterpret_cast<float*>(SH);   // fc y buffer aliases SH after loop

    const int tid = threadIdx.x;
    const int lane = tid & 63, w = tid >> 6;     // wave 0..7
    const int q = lane >> 4, col = lane & 15;
    const int rb = blockIdx.x * Mrows;

    // resident W: tiles 2w, 2w+1 -> fp16 hi all 12 kb (96 regs) + fp8 lo kb4..11 (32 regs)
    hfrag wh[2][12];
    long  wl8[2][8];
    #pragma unroll
    for (int i = 0; i < 2; ++i) {
        #pragma unroll
        for (int kb = 0; kb < 12; ++kb) {
            int fid = (kb * 16 + (2 * w + i)) * 64 + lane;
            wh[i][kb] = *reinterpret_cast<const hfrag*>(&wfh[(size_t)fid * 4]);
        }
        #pragma unroll
        for (int kp = 0; kp < 8; ++kp) {
            int fid = ((kp + 4) * 16 + (2 * w + i)) * 64 + lane;
            wl8[i][kp] = *reinterpret_cast<const long*>(&wfl8[(size_t)fid * 2]);
        }
    }
    #pragma unroll
    for (int i = 0; i < 2; ++i) {
        #pragma unroll
        for (int kb = 0; kb < 12; ++kb) asm volatile("" : "+v"(wh[i][kb]));
        #pragma unroll
        for (int kp = 0; kp < 8; ++kp) asm volatile("" : "+v"(wl8[i][kp]));
    }

    // bias folded into MFMA C-init
    f4v bcv[2];
    #pragma unroll
    for (int i = 0; i < 2; ++i)
        #pragma unroll
        for (int r = 0; r < 4; ++r) {
            int n = (2 * w + i) * 16 + 4 * q + r;
            bcv[i][r] = b_ih[n] + b_hh[n];
        }
    const int len_c = x_len[rb + col];
    int tmax = len_c;
    #pragma unroll
    for (int m = 1; m < 16; m <<= 1) {
        int o = __shfl_xor(tmax, m, 64);
        tmax = tmax > o ? tmax : o;
    }

    // token table, transposed [t*16 + m] (conflict-free per-step reads)
    for (int u = tid; u < Mrows * Sv; u += 512) {
        int tt = u & 63, m = u >> 6;
        sidx[tt * 16 + m] = x_in[(rb + m) * Sv + tt];
    }
    // zero h + A8 region of buffer 0 (words 1024..4095; SW permutes within)
    for (int u = tid; u < 3072; u += 512) SH[1024 + u] = 0u;

    // emb staging geometry: thread stages 4 consecutive k of one row (f16 only)
    const int em = tid >> 5;            // row 0..15
    const int ek = (tid & 31) * 4;      // k 0..124
    const int eo = (ek >> 5) * 256 + ((((ek >> 3) & 3) * 16 + em) * 4) + (((ek >> 2) & 1) * 2);

    // stage emb for t=0; prefetch row for t=1 (depth-2 pipeline)
    {
        int tok0 = x_in[(rb + em) * Sv + 0];
        float4 e0 = *(const float4*)&emb[(size_t)tok0 * Ev + ek];
        *reinterpret_cast<uint2*>(&SH[SW(eo)]) =
            make_uint2(pk_h2(e0.x, e0.y), pk_h2(e0.z, e0.w));
    }
    float4 ev_cur;
    {
        int tok1 = x_in[(rb + em) * Sv + 1];
        ev_cur = *(const float4*)&emb[(size_t)tok1 * Ev + ek];
    }
    __syncthreads();

    #pragma unroll 1
    for (int t = 0; t < tmax; ++t) {
        const int rbuf = (t & 1) * WRDS;
        const int wbuf = ((t + 1) & 1) * WRDS;

        // prefetch emb row for t+2 (full step of latency budget)
        float4 ev_next;
        if (t + 2 < Sv) {
            int tok = sidx[(t + 2) * 16 + em];
            ev_next = *(const float4*)&emb[(size_t)tok * Ev + ek];
        }

        // 8 accumulator chains, bias folded into the even f16 chains
        f4v aHe0 = bcv[0], aHe1 = bcv[1];
        f4v z = {0.f, 0.f, 0.f, 0.f};
        f4v aHo0 = z, aHo1 = z, a8e0 = z, a8e1 = z, a8o0 = z, a8o1 = z;

        #pragma unroll
        for (int kb = 0; kb < 4; ++kb) {
            hfrag ah = *reinterpret_cast<const hfrag*>(&SH[rbuf + SW(kb * 256 + lane * 4)]);
            if (kb & 1) {
                aHo0 = __builtin_amdgcn_mfma_f32_16x16x32_f16(wh[0][kb], ah, aHo0, 0, 0, 0);
                aHo1 = __builtin_amdgcn_mfma_f32_16x16x32_f16(wh[1][kb], ah, aHo1, 0, 0, 0);
            } else {
                aHe0 = __builtin_amdgcn_mfma_f32_16x16x32_f16(wh[0][kb], ah, aHe0, 0, 0, 0);
                aHe1 = __builtin_amdgcn_mfma_f32_16x16x32_f16(wh[1][kb], ah, aHe1, 0, 0, 0);
            }
        }
        #pragma unroll
        for (int p = 0; p < 4; ++p) {
            const int kbE = 4 + 2 * p;
            hfrag ahE = *reinterpret_cast<const hfrag*>(&SH[rbuf + SW(kbE * 256 + lane * 4)]);
            hfrag ahO = *reinterpret_cast<const hfrag*>(&SH[rbuf + SW((kbE + 1) * 256 + lane * 4)]);
            uint4 a8p = *reinterpret_cast<const uint4*>(&SH[rbuf + SW(3072 + p * 256 + lane * 4)]);
            long a8E = mklong(a8p.x, a8p.y), a8O = mklong(a8p.z, a8p.w);
            aHe0 = __builtin_amdgcn_mfma_f32_16x16x32_f16(wh[0][kbE], ahE, aHe0, 0, 0, 0);
            aHe1 = __builtin_amdgcn_mfma_f32_16x16x32_f16(wh[1][kbE], ahE, aHe1, 0, 0, 0);
            a8e0 = __builtin_amdgcn_mfma_f32_16x16x32_fp8_fp8(wl8[0][2 * p], a8E, a8e0, 0, 0, 0);
            a8e1 = __builtin_amdgcn_mfma_f32_16x16x32_fp8_fp8(wl8[1][2 * p], a8E, a8e1, 0, 0, 0);
            aHo0 = __builtin_amdgcn_mfma_f32_16x16x32_f16(wh[0][kbE + 1], ahO, aHo0, 0, 0, 0);
            aHo1 = __builtin_amdgcn_mfma_f32_16x16x32_f16(wh[1][kbE + 1], ahO, aHo1, 0, 0, 0);
            a8o0 = __builtin_amdgcn_mfma_f32_16x16x32_fp8_fp8(wl8[0][2 * p + 1], a8O, a8o0, 0, 0, 0);
            a8o1 = __builtin_amdgcn_mfma_f32_16x16x32_fp8_fp8(wl8[1][2 * p + 1], a8O, a8o1, 0, 0, 0);
        }

        // epilogue: lane holds h[m=col][n = ti*16 + 4q + r]
        #pragma unroll
        for (int i = 0; i < 2; ++i) {
            f4v s  = (i == 0) ? (aHe0 + aHo0) : (aHe1 + aHo1);
            f4v s8 = (i == 0) ? (a8e0 + a8o0) : (a8e1 + a8o1);
            const int ti = 2 * w + i;
            float hv[4];
            #pragma unroll
            for (int r = 0; r < 4; ++r)
                hv[r] = fast_tanh(s[r] + s8[r] * FP8_DESCALE);
            const int dl = ((ti & 1) * 2 + (q >> 1)) * 16 + col;
            const uint2 hu = make_uint2(pk_h2(hv[0], hv[1]), pk_h2(hv[2], hv[3]));
            const unsigned a8w = pk_fp8x4(hv[0], hv[1], hv[2], hv[3], FP8_ASCALE);
            const int oAH = (4 + (ti >> 1)) * 256 + dl * 4 + (q & 1) * 2;
            const int oA8 = 3072 + (ti >> 2) * 256 + dl * 4 + ((ti >> 1) & 1) * 2 + (q & 1);
            *reinterpret_cast<uint2*>(&SH[wbuf + SW(oAH)]) = hu;
            SH[wbuf + SW(oA8)] = a8w;
            if (t == len_c - 1) {
                const int oLH = (ti >> 1) * 256 + dl * 4 + (q & 1) * 2;
                const int oL8 = 2048 + (ti >> 2) * 256 + dl * 4 + ((ti >> 1) & 1) * 2 + (q & 1);
                *reinterpret_cast<uint2*>(&LF[SW(oLH)]) = hu;
                LF[SW(oL8)] = a8w;
            }
        }
        // stage emb for step t+1 (value prefetched at t-1)
        if (t + 1 < Sv) {
            *reinterpret_cast<uint2*>(&SH[wbuf + SW(eo)]) =
                make_uint2(pk_h2(ev_cur.x, ev_cur.y), pk_h2(ev_cur.z, ev_cur.w));
        }
        ev_cur = ev_next;
        __syncthreads();
    }

    // ---- fused FC1 (MFMA, fp16+fp8) on LF ----
    f4v f0, f1, f80, f81;
    {
        float4 bb0 = *(const float4*)&b1[(2 * w) * 16 + 4 * q];
        float4 bb1 = *(const float4*)&b1[(2 * w + 1) * 16 + 4 * q];
        f0 = (f4v){bb0.x, bb0.y, bb0.z, bb0.w};
        f1 = (f4v){bb1.x, bb1.y, bb1.z, bb1.w};
        f4v z = {0.f, 0.f, 0.f, 0.f};
        f80 = z; f81 = z;
    }
    uint4 a8p;
    #pragma unroll
    for (int kb = 0; kb < 8; ++kb) {
        hfrag ah = *reinterpret_cast<const hfrag*>(&LF[SW(kb * 256 + lane * 4)]);
        if ((kb & 1) == 0)
            a8p = *reinterpret_cast<const uint4*>(&LF[SW(2048 + (kb >> 1) * 256 + lane * 4)]);
        long a8 = (kb & 1) ? mklong(a8p.z, a8p.w) : mklong(a8p.x, a8p.y);
        int fid0 = (kb * 16 + 2 * w) * 64 + lane;
        int fid1 = fid0 + 64;
        hfrag w0 = *reinterpret_cast<const hfrag*>(&wf1h[(size_t)fid0 * 4]);
        hfrag w1 = *reinterpret_cast<const hfrag*>(&wf1h[(size_t)fid1 * 4]);
        long  l0 = *reinterpret_cast<const long*>(&wf1l8[(size_t)fid0 * 2]);
        long  l1 = *reinterpret_cast<const long*>(&wf1l8[(size_t)fid1 * 2]);
        f0  = __builtin_amdgcn_mfma_f32_16x16x32_f16(w0, ah, f0, 0, 0, 0);
        f1  = __builtin_amdgcn_mfma_f32_16x16x32_f16(w1, ah, f1, 0, 0, 0);
        f80 = __builtin_amdgcn_mfma_f32_16x16x32_fp8_fp8(l0, a8, f80, 0, 0, 0);
        f81 = __builtin_amdgcn_mfma_f32_16x16x32_fp8_fp8(l1, a8, f81, 0, 0, 0);
    }

    // y = relu(...) into yb (aliases SH; step buffers dead here)
    #pragma unroll
    for (int i = 0; i < 2; ++i) {
        int n0 = (2 * w + i) * 16 + 4 * q;
        f4v s = (i == 0) ? f0 : f1;
        f4v s8 = (i == 0) ? f80 : f81;
        float4 yv;
        yv.x = fmaxf(s[0] + s8[0] * FP8_DESCALE, 0.f);
        yv.y = fmaxf(s[1] + s8[1] * FP8_DESCALE, 0.f);
        yv.z = fmaxf(s[2] + s8[2] * FP8_DESCALE, 0.f);
        yv.w = fmaxf(s[3] + s8[3] * FP8_DESCALE, 0.f);
        *reinterpret_cast<float4*>(&yb[col * 260 + n0]) = yv;
    }
    __syncthreads();

    // ---- FC2: 16 x 18 dots of length 256 ----
    if (tid < Mrows * Cv) {
        int r = tid & 15, cc = tid >> 4;
        float s = b2[cc];
        #pragma unroll 8
        for (int k4 = 0; k4 < Hv / 4; ++k4) {
            float4 yv = *reinterpret_cast<const float4*>(&yb[r * 260 + 4 * k4]);
            float4 wv2 = *(const float4*)&W2[cc * Hv + 4 * k4];
            s = fmaf(yv.x, wv2.x, s);
            s = fmaf(yv.y, wv2.y, s);
            s = fmaf(yv.z, wv2.z, s);
            s = fmaf(yv.w, wv2.w, s);
        }
        out[(rb + r) * Cv + cc] = s;
    }
}

extern "C" void kernel_launch(void* const* d_in, const int* in_sizes, int n_in,
                              void* d_out, int out_size, void* d_ws, size_t ws_size,
                              hipStream_t stream) {
    const int*   x_in  = (const int*)  d_in[0];
    const int*   x_len = (const int*)  d_in[1];
    const float* emb   = (const float*)d_in[2];
    const float* W_ih  = (const float*)d_in[3];
    const float* W_hh  = (const float*)d_in[4];
    const float* b_ih  = (const float*)d_in[5];
    const float* b_hh  = (const float*)d_in[6];
    const float* W1    = (const float*)d_in[7];
    const float* b1    = (const float*)d_in[8];
    const float* W2    = (const float*)d_in[9];
    const float* b2    = (const float*)d_in[10];
    float* out = (float*)d_out;

    unsigned* wfh   = (unsigned*)d_ws;        // 12288*16 B
    unsigned* wfl8  = wfh + 12288 * 4;        // 12288*8 B
    unsigned* wf1h  = wfl8 + 12288 * 2;       // 8192*16 B
    unsigned* wf1l8 = wf1h + 8192 * 4;        // 8192*8 B

    build_frags<<<80, 256, 0, stream>>>(W_ih, W_hh, W1, wfh, wfl8, wf1h, wf1l8);
    rnn_fused<<<Bv / Mrows, 512, 0, stream>>>(x_in, x_len, emb, wfh, wfl8,
                                              wf1h, wf1l8, b_ih, b_hh,
                                              b1, W2, b2, out);
}